// Round 2
// baseline (15034.468 us; speedup 1.0000x reference)
//
#include <hip/hip_runtime.h>
#include <hip/hip_bf16.h>

typedef unsigned short u16;
typedef unsigned int   u32;
typedef short short8 __attribute__((ext_vector_type(8)));
typedef float f32x4  __attribute__((ext_vector_type(4)));
typedef u16   u16x4  __attribute__((ext_vector_type(4)));

#define T_STEPS 512
#define BATCH   64
#define HD      1024
#define NBLK    256
#define NTHR    256
#define WKS     2056   // K-stride in LDS elems: 2048 + 8 pad (16B-aligned, 2-way bank alias = free)

// LDS layout (bytes)
#define W_BYTES    (16 * WKS * 2)        // 65792: 16 gate-cols x 2048 K (bf16), k-contiguous
#define G_OFF      W_BYTES
#define G_BYTES    (BATCH * 17 * 4)      // 4352: g scratch, padded stride 17
#define C_OFF      (G_OFF + G_BYTES)
#define C_BYTES    (BATCH * 4 * 4)       // 1024: c state fp32 (persistent)
#define B_OFF      (C_OFF + C_BYTES)
#define B_BYTES    (16 * 4)
#define F_OFF      (B_OFF + B_BYTES)     // dtype-detect flag
#define SMEM_BYTES (F_OFF + 16)          // 71248 -> 1 block/CU, 256 blocks co-resident

__device__ __forceinline__ float sigm(float x) { return 1.f / (1.f + __expf(-x)); }
__device__ __forceinline__ float tanh_(float x) {
    float ax = __builtin_fabsf(x);
    float e  = __expf(-2.f * ax);
    float r  = (1.f - e) / (1.f + e);
    return x < 0.f ? -r : r;
}
__device__ __forceinline__ short bfb(float f) {          // fp32 -> bf16 bits (RNE)
    __hip_bfloat16 h = __float2bfloat16(f);
    return *(short*)&h;
}

// Dtype probe: x ~ N(0,1). If x is PACKED BF16, the low u16 of each u32 is a
// bf16 sample -> exponent field in [100,140] essentially always (count ~256/256).
// If x is FP32, the low u16 is mantissa junk -> exponent uniform (count ~31/256).
// Threshold 128 is ~18 sigma from both. Deterministic, same result in every block.
__device__ int detect_bf16(const u32* __restrict__ x) {
    int c = 0;
#pragma unroll 8
    for (int i = 0; i < 256; ++i) {
        u32 e = (x[i] >> 7) & 0xFF;
        c += (e >= 100 && e <= 140) ? 1 : 0;
    }
    return c >= 128;
}

// Monotonic-counter grid barrier. All NBLK blocks co-resident (1 block/CU).
// Release: syncthreads drains block's h-stores to XCD L2; agent fence writes
// back L2 to the coherence point; release-add publishes. Acquire: agent fence
// invalidates L1+L2 so next h reads miss to the coherence point.
__device__ __forceinline__ void grid_barrier(int* cnt, int target) {
    __syncthreads();
    if (threadIdx.x == 0) {
        __threadfence();
        __hip_atomic_fetch_add(cnt, 1, __ATOMIC_RELEASE, __HIP_MEMORY_SCOPE_AGENT);
        while (__hip_atomic_load(cnt, __ATOMIC_RELAXED, __HIP_MEMORY_SCOPE_AGENT) < target)
            __builtin_amdgcn_s_sleep(1);
        __threadfence();
    }
    __syncthreads();
}

// Prologue: if x is fp32 and ws has room, pre-convert x -> bf16 once (halves
// per-step L2 A-traffic in the persistent kernel). Self-detects dtype.
extern "C" __global__ void __launch_bounds__(256)
cvt_x_kernel(const void* __restrict__ x, u16* __restrict__ xb, int n4)
{
    __shared__ int flg;
    if (threadIdx.x == 0) flg = detect_bf16((const u32*)x);
    __syncthreads();
    if (flg) return;                       // already bf16: persistent reads x directly
    const float4* xf = (const float4*)x;
    u16x4* xo = (u16x4*)xb;
    for (int i = blockIdx.x * blockDim.x + threadIdx.x; i < n4;
         i += gridDim.x * blockDim.x) {
        float4 v = xf[i];
        u16x4 o;
        o[0] = (u16)bfb(v.x); o[1] = (u16)bfb(v.y);
        o[2] = (u16)bfb(v.z); o[3] = (u16)bfb(v.w);
        xo[i] = o;
    }
}

extern "C" __global__ void __launch_bounds__(NTHR)
lstm_persistent(const void* __restrict__ x,
                const void* __restrict__ Wxf, const void* __restrict__ Wxi,
                const void* __restrict__ Wxg, const void* __restrict__ Wxo,
                const void* __restrict__ Whf, const void* __restrict__ Whi,
                const void* __restrict__ Whg, const void* __restrict__ Who,
                const void* __restrict__ bxf, const void* __restrict__ bxi,
                const void* __restrict__ bxg, const void* __restrict__ bxo,
                const void* __restrict__ bhf, const void* __restrict__ bhi,
                const void* __restrict__ bhg, const void* __restrict__ bho,
                u16* __restrict__ h0buf, u16* __restrict__ h1buf,
                u16* __restrict__ xb, int* __restrict__ cnt, void* __restrict__ outv)
{
    extern __shared__ char smem[];
    u16*   w_lds = (u16*)smem;
    float* g_lds = (float*)(smem + G_OFF);
    float* c_lds = (float*)(smem + C_OFF);
    float* b_lds = (float*)(smem + B_OFF);
    int*   f_lds = (int*)(smem + F_OFF);

    const int tid = threadIdx.x;
    const int blk = blockIdx.x;

    if (tid == 0) f_lds[0] = detect_bf16((const u32*)x);
    __syncthreads();
    const int bf16mode = f_lds[0];

    // ---- Stage weight slice once as bf16: cols [4*blk,4*blk+4) of gates f,i,g,o.
    //      LDS: [gate-col][K], K = 1024 x-side then 1024 h-side, k-contiguous.
    {
        const int gate = tid >> 6;   // wave-uniform
        const int kb   = tid & 63;
        const void* WX[4] = {Wxf, Wxi, Wxg, Wxo};
        const void* WH[4] = {Whf, Whi, Whg, Who};
        for (int it = 0; it < 16; ++it) {
            int k = it * 64 + kb;
            u16 vx[4], vh[4];
            if (bf16mode) {
                u16x4 a = *(const u16x4*)((const u16*)WX[gate] + (size_t)k * HD + blk * 4);
                u16x4 b = *(const u16x4*)((const u16*)WH[gate] + (size_t)k * HD + blk * 4);
#pragma unroll
                for (int ci = 0; ci < 4; ++ci) { vx[ci] = a[ci]; vh[ci] = b[ci]; }
            } else {
                float4 a = *(const float4*)((const float*)WX[gate] + (size_t)k * HD + blk * 4);
                float4 b = *(const float4*)((const float*)WH[gate] + (size_t)k * HD + blk * 4);
                vx[0] = (u16)bfb(a.x); vx[1] = (u16)bfb(a.y);
                vx[2] = (u16)bfb(a.z); vx[3] = (u16)bfb(a.w);
                vh[0] = (u16)bfb(b.x); vh[1] = (u16)bfb(b.y);
                vh[2] = (u16)bfb(b.z); vh[3] = (u16)bfb(b.w);
            }
#pragma unroll
            for (int ci = 0; ci < 4; ++ci) {
                w_lds[(gate * 4 + ci) * WKS + k]        = vx[ci];
                w_lds[(gate * 4 + ci) * WKS + 1024 + k] = vh[ci];
            }
        }
    }
    for (int i = tid; i < BATCH * 4; i += NTHR) c_lds[i] = 0.f;   // c0 = 0
    if (tid < 16) {
        const void* BX[4] = {bxf, bxi, bxg, bxo};
        const void* BH[4] = {bhf, bhi, bhg, bho};
        int gate = tid >> 2, hc = blk * 4 + (tid & 3);
        float v;
        if (bf16mode)
            v = __bfloat162float(((const __hip_bfloat16*)BX[gate])[hc]) +
                __bfloat162float(((const __hip_bfloat16*)BH[gate])[hc]);
        else
            v = ((const float*)BX[gate])[hc] + ((const float*)BH[gate])[hc];
        b_lds[tid] = v;
    }
    __syncthreads();

    // MFMA 16x16x32 bf16 fragments: A[m=lane&15][k=quad*8+j],
    // B[k=quad*8+j][n=lane&15], C/D: col=lane&15, row=quad*4+reg.
    const int wv   = tid >> 6;       // wave = M-tile (16 batch rows)
    const int lane = tid & 63;
    const int c16  = lane & 15;
    const int quad = lane >> 4;
    const int arow = wv * 16 + c16;  // batch row this lane loads for A

    const int use16 = bf16mode || (xb != nullptr);
    const u16*   x16l = nullptr;
    const float* xf_l = nullptr;
    if (use16) {
        const u16* x16 = bf16mode ? (const u16*)x : xb;
        x16l = x16 + (size_t)arow * T_STEPS * HD + quad * 8;
    } else {
        xf_l = (const float*)x + (size_t)arow * T_STEPS * HD + quad * 8;
    }
    const u16* wbase = w_lds + c16 * WKS + quad * 8;

    const int r    = tid >> 2;       // gate-phase batch row
    const int j    = tid & 3;        // gate-phase h-col within block
    const int hcol = blk * 4 + j;

    u16* hbufs[2] = {h0buf, h1buf};
    int p = 0;

    for (int t = 0; t < T_STEPS; ++t) {
        f32x4 acc0 = {0.f, 0.f, 0.f, 0.f};
        f32x4 acc1 = {0.f, 0.f, 0.f, 0.f};

        // ---- x-side K: 1024
        if (use16) {
            const u16* xp = x16l + (size_t)t * HD;
#pragma unroll 4
            for (int kc = 0; kc < 32; kc += 2) {
                short8 a0 = *(const short8*)(xp + kc * 32);
                short8 b0 = *(const short8*)(wbase + kc * 32);
                short8 a1 = *(const short8*)(xp + kc * 32 + 32);
                short8 b1 = *(const short8*)(wbase + kc * 32 + 32);
                acc0 = __builtin_amdgcn_mfma_f32_16x16x32_bf16(a0, b0, acc0, 0, 0, 0);
                acc1 = __builtin_amdgcn_mfma_f32_16x16x32_bf16(a1, b1, acc1, 0, 0, 0);
            }
        } else {
            const float* xp = xf_l + (size_t)t * HD;
#pragma unroll 4
            for (int kc = 0; kc < 32; kc += 2) {
                float4 fa = *(const float4*)(xp + kc * 32);
                float4 fb = *(const float4*)(xp + kc * 32 + 4);
                float4 fc = *(const float4*)(xp + kc * 32 + 32);
                float4 fd = *(const float4*)(xp + kc * 32 + 36);
                short8 a0 = {bfb(fa.x), bfb(fa.y), bfb(fa.z), bfb(fa.w),
                             bfb(fb.x), bfb(fb.y), bfb(fb.z), bfb(fb.w)};
                short8 a1 = {bfb(fc.x), bfb(fc.y), bfb(fc.z), bfb(fc.w),
                             bfb(fd.x), bfb(fd.y), bfb(fd.z), bfb(fd.w)};
                short8 b0 = *(const short8*)(wbase + kc * 32);
                short8 b1 = *(const short8*)(wbase + kc * 32 + 32);
                acc0 = __builtin_amdgcn_mfma_f32_16x16x32_bf16(a0, b0, acc0, 0, 0, 0);
                acc1 = __builtin_amdgcn_mfma_f32_16x16x32_bf16(a1, b1, acc1, 0, 0, 0);
            }
        }
        // ---- h-side K: 1024 (skip at t==0: h0 == 0)
        if (t > 0) {
            const u16* hp = hbufs[p] + (size_t)arow * HD + quad * 8;
#pragma unroll 4
            for (int kc = 0; kc < 32; kc += 2) {
                short8 a0 = *(const short8*)(hp + kc * 32);
                short8 b0 = *(const short8*)(wbase + 1024 + kc * 32);
                short8 a1 = *(const short8*)(hp + kc * 32 + 32);
                short8 b1 = *(const short8*)(wbase + 1024 + kc * 32 + 32);
                acc0 = __builtin_amdgcn_mfma_f32_16x16x32_bf16(a0, b0, acc0, 0, 0, 0);
                acc1 = __builtin_amdgcn_mfma_f32_16x16x32_bf16(a1, b1, acc1, 0, 0, 0);
            }
        }
        f32x4 acc = acc0 + acc1;

        // dump g to LDS (stride 17 breaks conflicts)
        const int rr = wv * 16 + quad * 4;
#pragma unroll
        for (int i2 = 0; i2 < 4; ++i2)
            g_lds[(rr + i2) * 17 + c16] = acc[i2];
        __syncthreads();

        // gate phase: one (row, hcol) pair per thread; c stays fp32 in LDS
        float gf = g_lds[r * 17 + j]      + b_lds[j];
        float gi = g_lds[r * 17 + 4 + j]  + b_lds[4 + j];
        float gg = g_lds[r * 17 + 8 + j]  + b_lds[8 + j];
        float go = g_lds[r * 17 + 12 + j] + b_lds[12 + j];
        float fg = sigm(gf), ig = sigm(gi), og = sigm(go);
        float gt = tanh_(gg);
        float cold = c_lds[r * 4 + j];
        float cnew = fg * cold + ig * gt;
        c_lds[r * 4 + j] = cnew;
        float hv = tanh_(cnew) * og;
        __hip_bfloat16 hb = __float2bfloat16(hv);
        u16 hbits = *(u16*)&hb;

        if (t < T_STEPS - 1) {
            hbufs[p ^ 1][(size_t)r * HD + hcol] = hbits;
            grid_barrier(cnt, (t + 1) * NBLK);
            p ^= 1;
        } else {
            if (bf16mode) {
                u16* o = (u16*)outv;
                o[(size_t)r * HD + hcol] = hbits;
                __hip_bfloat16 cb = __float2bfloat16(cnew);
                o[(size_t)BATCH * HD + (size_t)r * HD + hcol] = *(u16*)&cb;
            } else {
                float* o = (float*)outv;
                o[(size_t)r * HD + hcol] = hv;                        // h_T
                o[(size_t)BATCH * HD + (size_t)r * HD + hcol] = cnew; // c_T
            }
        }
    }
}

extern "C" void kernel_launch(void* const* d_in, const int* in_sizes, int n_in,
                              void* d_out, int out_size, void* d_ws, size_t ws_size,
                              hipStream_t stream) {
    (void)in_sizes; (void)n_in; (void)out_size;
    const void* x   = d_in[0];
    const void* Wii = d_in[1];  const void* Whi = d_in[2];
    const void* Wif = d_in[3];  const void* Whf = d_in[4];
    const void* Wig = d_in[5];  const void* Whg = d_in[6];
    const void* Wio = d_in[7];  const void* Who = d_in[8];
    const void* bii = d_in[9];  const void* bhi = d_in[10];
    const void* bif = d_in[11]; const void* bhf = d_in[12];
    const void* big = d_in[13]; const void* bhg = d_in[14];
    const void* bio = d_in[15]; const void* bho = d_in[16];

    int* cnt = (int*)d_ws;
    u16* h0  = (u16*)((char*)d_ws + 256);          // 2x 128KB h double-buffer (bf16)
    u16* h1  = h0 + BATCH * HD;
    size_t xb_off = 256 + (size_t)2 * BATCH * HD * 2;                 // 262400 (16B-aligned)
    size_t need   = xb_off + (size_t)BATCH * T_STEPS * HD * 2;        // ~67.4 MB
    u16* xb = (ws_size >= need) ? (u16*)((char*)d_ws + xb_off) : nullptr;

    hipMemsetAsync(d_ws, 0, 256, stream);          // zero barrier counter (graph-safe)
    if (xb)
        hipLaunchKernelGGL(cvt_x_kernel, dim3(2048), dim3(256), 0, stream,
                           x, xb, (BATCH * T_STEPS * HD) / 4);

    hipFuncSetAttribute((const void*)lstm_persistent,
                        hipFuncAttributeMaxDynamicSharedMemorySize, SMEM_BYTES);
    hipLaunchKernelGGL(lstm_persistent, dim3(NBLK), dim3(NTHR), SMEM_BYTES, stream,
                       x, Wif, Wii, Wig, Wio, Whf, Whi, Whg, Who,
                       bif, bii, big, bio, bhf, bhi, bhg, bho,
                       h0, h1, xb, cnt, d_out);
}

// Round 3
// 9744.450 us; speedup vs baseline: 1.5429x; 1.5429x over previous
//
#include <hip/hip_runtime.h>
#include <hip/hip_bf16.h>

typedef unsigned short u16;
typedef unsigned int   u32;
typedef short short8 __attribute__((ext_vector_type(8)));
typedef float f32x4  __attribute__((ext_vector_type(4)));
typedef u16   u16x4  __attribute__((ext_vector_type(4)));

#define T_STEPS 512
#define BATCH   64
#define HD      1024
#define NBLK    128    // 32 gate-cols per block
#define NTHR    256
#define NCOL    32
#define WKS     2056   // K-stride in LDS elems: 2048 + 8 pad (16B-aligned)

// LDS layout (bytes)
#define W_BYTES    (NCOL * WKS * 2)      // 131584
#define G_OFF      W_BYTES
#define G_STRIDE   33
#define G_BYTES    (BATCH * G_STRIDE * 4) // 8448
#define C_OFF      (G_OFF + G_BYTES)
#define C_BYTES    (BATCH * 8 * 4)        // 2048
#define B_OFF      (C_OFF + C_BYTES)
#define B_BYTES    (NCOL * 4)             // 128
#define F_OFF      (B_OFF + B_BYTES)
#define SMEM_BYTES (F_OFF + 16)           // ~142 KB < 160 KB -> 1 block/CU

__device__ __forceinline__ float sigm(float x) { return 1.f / (1.f + __expf(-x)); }
__device__ __forceinline__ float tanh_(float x) {
    float ax = __builtin_fabsf(x);
    float e  = __expf(-2.f * ax);
    float r  = (1.f - e) / (1.f + e);
    return x < 0.f ? -r : r;
}
__device__ __forceinline__ short bfb(float f) {          // fp32 -> bf16 bits (RNE)
    __hip_bfloat16 h = __float2bfloat16(f);
    return *(short*)&h;
}

// Dtype probe (see round-1 notes): packed-bf16 x -> low-u16 exponent in [100,140]
// ~always; fp32 x -> mantissa junk, ~uniform. 18-sigma separation at threshold 128.
__device__ int detect_bf16(const u32* __restrict__ x) {
    int c = 0;
#pragma unroll 8
    for (int i = 0; i < 256; ++i) {
        u32 e = (x[i] >> 7) & 0xFF;
        c += (e >= 100 && e <= 140) ? 1 : 0;
    }
    return c >= 128;
}

// Prologue: if x is fp32 and ws has room, pre-convert x -> bf16 once.
extern "C" __global__ void __launch_bounds__(256)
cvt_x_kernel(const void* __restrict__ x, u16* __restrict__ xb, int n4)
{
    __shared__ int flg;
    if (threadIdx.x == 0) flg = detect_bf16((const u32*)x);
    __syncthreads();
    if (flg) return;
    const float4* xf = (const float4*)x;
    u16x4* xo = (u16x4*)xb;
    for (int i = blockIdx.x * blockDim.x + threadIdx.x; i < n4;
         i += gridDim.x * blockDim.x) {
        float4 v = xf[i];
        u16x4 o;
        o[0] = (u16)bfb(v.x); o[1] = (u16)bfb(v.y);
        o[2] = (u16)bfb(v.z); o[3] = (u16)bfb(v.w);
        xo[i] = o;
    }
}

extern "C" __global__ void __launch_bounds__(NTHR)
lstm_persistent(const void* __restrict__ x,
                const void* __restrict__ Wxf, const void* __restrict__ Wxi,
                const void* __restrict__ Wxg, const void* __restrict__ Wxo,
                const void* __restrict__ Whf, const void* __restrict__ Whi,
                const void* __restrict__ Whg, const void* __restrict__ Who,
                const void* __restrict__ bxf, const void* __restrict__ bxi,
                const void* __restrict__ bxg, const void* __restrict__ bxo,
                const void* __restrict__ bhf, const void* __restrict__ bhi,
                const void* __restrict__ bhg, const void* __restrict__ bho,
                u16* __restrict__ h0buf, u16* __restrict__ h1buf,
                u16* __restrict__ xb, int* __restrict__ flags,
                void* __restrict__ outv)
{
    extern __shared__ char smem[];
    u16*   w_lds = (u16*)smem;
    float* g_lds = (float*)(smem + G_OFF);
    float* c_lds = (float*)(smem + C_OFF);
    float* b_lds = (float*)(smem + B_OFF);
    int*   f_lds = (int*)(smem + F_OFF);

    const int tid = threadIdx.x;
    const int blk = blockIdx.x;

    if (tid == 0) f_lds[0] = detect_bf16((const u32*)x);
    __syncthreads();
    const int bf16mode = f_lds[0];

    // ---- Stage weight slice once (bf16): cols [8*blk, 8*blk+8) of gates f,i,g,o.
    //      LDS: [gate-col][K], K = 1024 x-side then 1024 h-side, k-contiguous.
    {
        const int gate = tid >> 6;   // wave-uniform
        const int kb   = tid & 63;
        const void* WX[4] = {Wxf, Wxi, Wxg, Wxo};
        const void* WH[4] = {Whf, Whi, Whg, Who};
        for (int it = 0; it < 16; ++it) {
            int k = it * 64 + kb;
            u16 vx[8], vh[8];
            if (bf16mode) {
                short8 a = *(const short8*)((const u16*)WX[gate] + (size_t)k * HD + blk * 8);
                short8 b = *(const short8*)((const u16*)WH[gate] + (size_t)k * HD + blk * 8);
#pragma unroll
                for (int ci = 0; ci < 8; ++ci) { vx[ci] = (u16)a[ci]; vh[ci] = (u16)b[ci]; }
            } else {
                const float* px = (const float*)WX[gate] + (size_t)k * HD + blk * 8;
                const float* ph = (const float*)WH[gate] + (size_t)k * HD + blk * 8;
                float4 a0 = *(const float4*)px, a1 = *(const float4*)(px + 4);
                float4 b0 = *(const float4*)ph, b1 = *(const float4*)(ph + 4);
                vx[0]=(u16)bfb(a0.x); vx[1]=(u16)bfb(a0.y); vx[2]=(u16)bfb(a0.z); vx[3]=(u16)bfb(a0.w);
                vx[4]=(u16)bfb(a1.x); vx[5]=(u16)bfb(a1.y); vx[6]=(u16)bfb(a1.z); vx[7]=(u16)bfb(a1.w);
                vh[0]=(u16)bfb(b0.x); vh[1]=(u16)bfb(b0.y); vh[2]=(u16)bfb(b0.z); vh[3]=(u16)bfb(b0.w);
                vh[4]=(u16)bfb(b1.x); vh[5]=(u16)bfb(b1.y); vh[6]=(u16)bfb(b1.z); vh[7]=(u16)bfb(b1.w);
            }
#pragma unroll
            for (int ci = 0; ci < 8; ++ci) {
                w_lds[(gate * 8 + ci) * WKS + k]        = vx[ci];
                w_lds[(gate * 8 + ci) * WKS + 1024 + k] = vh[ci];
            }
        }
    }
    for (int i = tid; i < BATCH * 8; i += NTHR) c_lds[i] = 0.f;   // c0 = 0
    if (tid < NCOL) {
        const void* BX[4] = {bxf, bxi, bxg, bxo};
        const void* BH[4] = {bhf, bhi, bhg, bho};
        int gate = tid >> 3, hc = blk * 8 + (tid & 7);
        float v;
        if (bf16mode)
            v = __bfloat162float(((const __hip_bfloat16*)BX[gate])[hc]) +
                __bfloat162float(((const __hip_bfloat16*)BH[gate])[hc]);
        else
            v = ((const float*)BX[gate])[hc] + ((const float*)BH[gate])[hc];
        b_lds[tid] = v;
    }
    __syncthreads();

    // MFMA 16x16x32 bf16: A[m=lane&15][k=quad*8+j], B[k=quad*8+j][n=lane&15],
    // C/D: col=lane&15, row=quad*4+reg.
    const int wv   = tid >> 6;       // wave = M-tile (16 batch rows)
    const int lane = tid & 63;
    const int c16  = lane & 15;
    const int quad = lane >> 4;
    const int arow = wv * 16 + c16;

    const int use16 = bf16mode || (xb != nullptr);
    const u16*   x16l = nullptr;
    const float* xf_l = nullptr;
    if (use16) {
        const u16* x16 = bf16mode ? (const u16*)x : xb;
        x16l = x16 + (size_t)arow * T_STEPS * HD + quad * 8;
    } else {
        xf_l = (const float*)x + (size_t)arow * T_STEPS * HD + quad * 8;
    }
    const u16* wb0 = w_lds + c16 * WKS + quad * 8;         // N-subtile 0: cols 0-15
    const u16* wb1 = w_lds + (16 + c16) * WKS + quad * 8;  // N-subtile 1: cols 16-31

    const int r  = tid >> 2;         // gate-phase batch row
    const int j4 = tid & 3;          // gate-phase h-col (j4 and j4+4)

    u16* hbufs[2] = {h0buf, h1buf};
    int p = 0;
    const int polll = tid & 63;      // poll lane: flags[polll], flags[64+polll]

    // x-side partials for t=0 (h-independent)
    f32x4 ax0 = {0.f,0.f,0.f,0.f}, ax1 = {0.f,0.f,0.f,0.f};
    {
        if (use16) {
            const u16* xp = x16l;
#pragma unroll 8
            for (int kc = 0; kc < 32; ++kc) {
                short8 a  = *(const short8*)(xp + kc * 32);
                short8 b0 = *(const short8*)(wb0 + kc * 32);
                short8 b1 = *(const short8*)(wb1 + kc * 32);
                ax0 = __builtin_amdgcn_mfma_f32_16x16x32_bf16(a, b0, ax0, 0, 0, 0);
                ax1 = __builtin_amdgcn_mfma_f32_16x16x32_bf16(a, b1, ax1, 0, 0, 0);
            }
        } else {
            const float* xp = xf_l;
#pragma unroll 4
            for (int kc = 0; kc < 32; ++kc) {
                float4 fa = *(const float4*)(xp + kc * 32);
                float4 fb = *(const float4*)(xp + kc * 32 + 4);
                short8 a = {bfb(fa.x), bfb(fa.y), bfb(fa.z), bfb(fa.w),
                            bfb(fb.x), bfb(fb.y), bfb(fb.z), bfb(fb.w)};
                short8 b0 = *(const short8*)(wb0 + kc * 32);
                short8 b1 = *(const short8*)(wb1 + kc * 32);
                ax0 = __builtin_amdgcn_mfma_f32_16x16x32_bf16(a, b0, ax0, 0, 0, 0);
                ax1 = __builtin_amdgcn_mfma_f32_16x16x32_bf16(a, b1, ax1, 0, 0, 0);
            }
        }
    }

    for (int t = 0; t < T_STEPS; ++t) {
        f32x4 a0 = ax0, a1 = ax1;

        if (t > 0) {
            // ---- flag barrier: wait until every block has published h_t.
            // Plain parallel stores + shared read polling -- no RMW serialization.
            while (true) {
                int fa = __hip_atomic_load(&flags[polll], __ATOMIC_RELAXED,
                                           __HIP_MEMORY_SCOPE_AGENT);
                int fb = __hip_atomic_load(&flags[64 + polll], __ATOMIC_RELAXED,
                                           __HIP_MEMORY_SCOPE_AGENT);
                if (__all(fa >= t && fb >= t)) break;
                __builtin_amdgcn_s_sleep(1);
            }
            __builtin_amdgcn_fence(__ATOMIC_ACQUIRE, "agent");   // inv L1/L2

            // ---- h-side K: 1024
            const u16* hp = hbufs[p] + (size_t)arow * HD + quad * 8;
#pragma unroll 8
            for (int kc = 0; kc < 32; ++kc) {
                short8 a  = *(const short8*)(hp + kc * 32);
                short8 b0 = *(const short8*)(wb0 + 1024 + kc * 32);
                short8 b1 = *(const short8*)(wb1 + 1024 + kc * 32);
                a0 = __builtin_amdgcn_mfma_f32_16x16x32_bf16(a, b0, a0, 0, 0, 0);
                a1 = __builtin_amdgcn_mfma_f32_16x16x32_bf16(a, b1, a1, 0, 0, 0);
            }
        }

        // dump g to LDS
        const int rr = wv * 16 + quad * 4;
#pragma unroll
        for (int i2 = 0; i2 < 4; ++i2) {
            g_lds[(rr + i2) * G_STRIDE + c16]      = a0[i2];
            g_lds[(rr + i2) * G_STRIDE + 16 + c16] = a1[i2];
        }
        __syncthreads();

        // gate phase: thread handles (row r, local h-cols j4 and j4+4)
        float hv[2]; float cv[2];
#pragma unroll
        for (int jj = 0; jj < 2; ++jj) {
            int hl = j4 + jj * 4;
            float gf = g_lds[r * G_STRIDE + hl]      + b_lds[hl];
            float gi = g_lds[r * G_STRIDE + 8 + hl]  + b_lds[8 + hl];
            float gg = g_lds[r * G_STRIDE + 16 + hl] + b_lds[16 + hl];
            float go = g_lds[r * G_STRIDE + 24 + hl] + b_lds[24 + hl];
            float fg = sigm(gf), ig = sigm(gi), og = sigm(go);
            float gt = tanh_(gg);
            float cnew = fg * c_lds[r * 8 + hl] + ig * gt;
            c_lds[r * 8 + hl] = cnew;
            cv[jj] = cnew;
            hv[jj] = tanh_(cnew) * og;
        }

        if (t < T_STEPS - 1) {
            u16* hn = hbufs[p ^ 1];
#pragma unroll
            for (int jj = 0; jj < 2; ++jj) {
                __hip_bfloat16 hb = __float2bfloat16(hv[jj]);
                hn[(size_t)r * HD + blk * 8 + j4 + jj * 4] = *(u16*)&hb;
            }
            __syncthreads();   // drains h stores (waitcnt before s_barrier) + g_lds WAR
            if (tid == 0) {
                __builtin_amdgcn_fence(__ATOMIC_RELEASE, "agent");   // wb L2 -> L3
                __hip_atomic_store(&flags[blk], t + 1, __ATOMIC_RELAXED,
                                   __HIP_MEMORY_SCOPE_AGENT);
            }
            p ^= 1;

            // ---- x-side partials for t+1: overlaps flag propagation
            ax0 = (f32x4){0.f,0.f,0.f,0.f};
            ax1 = (f32x4){0.f,0.f,0.f,0.f};
            if (use16) {
                const u16* xp = x16l + (size_t)(t + 1) * HD;
#pragma unroll 8
                for (int kc = 0; kc < 32; ++kc) {
                    short8 a  = *(const short8*)(xp + kc * 32);
                    short8 b0 = *(const short8*)(wb0 + kc * 32);
                    short8 b1 = *(const short8*)(wb1 + kc * 32);
                    ax0 = __builtin_amdgcn_mfma_f32_16x16x32_bf16(a, b0, ax0, 0, 0, 0);
                    ax1 = __builtin_amdgcn_mfma_f32_16x16x32_bf16(a, b1, ax1, 0, 0, 0);
                }
            } else {
                const float* xp = xf_l + (size_t)(t + 1) * HD;
#pragma unroll 4
                for (int kc = 0; kc < 32; ++kc) {
                    float4 fa = *(const float4*)(xp + kc * 32);
                    float4 fb = *(const float4*)(xp + kc * 32 + 4);
                    short8 a = {bfb(fa.x), bfb(fa.y), bfb(fa.z), bfb(fa.w),
                                bfb(fb.x), bfb(fb.y), bfb(fb.z), bfb(fb.w)};
                    short8 b0 = *(const short8*)(wb0 + kc * 32);
                    short8 b1 = *(const short8*)(wb1 + kc * 32);
                    ax0 = __builtin_amdgcn_mfma_f32_16x16x32_bf16(a, b0, ax0, 0, 0, 0);
                    ax1 = __builtin_amdgcn_mfma_f32_16x16x32_bf16(a, b1, ax1, 0, 0, 0);
                }
            }
        } else {
            // final step: write h_T and c_T
#pragma unroll
            for (int jj = 0; jj < 2; ++jj) {
                size_t idx = (size_t)r * HD + blk * 8 + j4 + jj * 4;
                if (bf16mode) {
                    u16* o = (u16*)outv;
                    __hip_bfloat16 hb = __float2bfloat16(hv[jj]);
                    __hip_bfloat16 cb = __float2bfloat16(cv[jj]);
                    o[idx] = *(u16*)&hb;
                    o[(size_t)BATCH * HD + idx] = *(u16*)&cb;
                } else {
                    float* o = (float*)outv;
                    o[idx] = hv[jj];
                    o[(size_t)BATCH * HD + idx] = cv[jj];
                }
            }
        }
    }
}

extern "C" void kernel_launch(void* const* d_in, const int* in_sizes, int n_in,
                              void* d_out, int out_size, void* d_ws, size_t ws_size,
                              hipStream_t stream) {
    (void)in_sizes; (void)n_in; (void)out_size;
    const void* x   = d_in[0];
    const void* Wii = d_in[1];  const void* Whi = d_in[2];
    const void* Wif = d_in[3];  const void* Whf = d_in[4];
    const void* Wig = d_in[5];  const void* Whg = d_in[6];
    const void* Wio = d_in[7];  const void* Who = d_in[8];
    const void* bii = d_in[9];  const void* bhi = d_in[10];
    const void* bif = d_in[11]; const void* bhf = d_in[12];
    const void* big = d_in[13]; const void* bhg = d_in[14];
    const void* bio = d_in[15]; const void* bho = d_in[16];

    int* flags = (int*)d_ws;                        // 128 flags (512 B), memset 0
    u16* h0 = (u16*)((char*)d_ws + 1024);           // 128 KB
    u16* h1 = h0 + BATCH * HD;                      // 128 KB
    size_t xb_off = 1024 + (size_t)2 * BATCH * HD * 2;            // 263168
    size_t need   = xb_off + (size_t)BATCH * T_STEPS * HD * 2;    // ~67.4 MB
    u16* xb = (ws_size >= need) ? (u16*)((char*)d_ws + xb_off) : nullptr;

    hipMemsetAsync(d_ws, 0, 1024, stream);
    if (xb)
        hipLaunchKernelGGL(cvt_x_kernel, dim3(2048), dim3(256), 0, stream,
                           x, xb, (BATCH * T_STEPS * HD) / 4);

    hipFuncSetAttribute((const void*)lstm_persistent,
                        hipFuncAttributeMaxDynamicSharedMemorySize, SMEM_BYTES);
    hipLaunchKernelGGL(lstm_persistent, dim3(NBLK), dim3(NTHR), SMEM_BYTES, stream,
                       x, Wif, Wii, Wig, Wio, Whf, Whi, Whg, Who,
                       bif, bii, big, bio, bhf, bhi, bhg, bho,
                       h0, h1, xb, flags, d_out);
}

// Round 4
// 7405.397 us; speedup vs baseline: 2.0302x; 1.3159x over previous
//
#include <hip/hip_runtime.h>
#include <hip/hip_bf16.h>

typedef unsigned short u16;
typedef unsigned int   u32;
typedef unsigned long long u64;
typedef short short8 __attribute__((ext_vector_type(8)));
typedef float f32x4  __attribute__((ext_vector_type(4)));
typedef u16   u16x4  __attribute__((ext_vector_type(4)));

#define T_STEPS 512
#define BATCH   64
#define HD      1024
#define NBLK    128    // 32 gate-cols per block
#define NTHR    256
#define NCOL    32
#define WKS     2056   // K-stride in LDS elems: 2048 + 8 pad (16B-aligned)

// LDS layout (bytes)
#define W_BYTES    (NCOL * WKS * 2)      // 131584
#define G_OFF      W_BYTES
#define G_STRIDE   33
#define G_BYTES    (BATCH * G_STRIDE * 4) // 8448
#define C_OFF      (G_OFF + G_BYTES)
#define C_BYTES    (BATCH * 8 * 4)        // 2048
#define B_OFF      (C_OFF + C_BYTES)
#define B_BYTES    (NCOL * 4)             // 128
#define F_OFF      (B_OFF + B_BYTES)
#define SMEM_BYTES (F_OFF + 16)           // ~142 KB < 160 KB -> 1 block/CU

__device__ __forceinline__ float sigm(float x) { return 1.f / (1.f + __expf(-x)); }
__device__ __forceinline__ float tanh_(float x) {
    float ax = __builtin_fabsf(x);
    float e  = __expf(-2.f * ax);
    float r  = (1.f - e) / (1.f + e);
    return x < 0.f ? -r : r;
}
__device__ __forceinline__ short bfb(float f) {          // fp32 -> bf16 bits (RNE)
    __hip_bfloat16 h = __float2bfloat16(f);
    return *(short*)&h;
}

// Dtype probe: packed-bf16 x -> low-u16 exponent in [100,140] ~always;
// fp32 x -> mantissa junk, ~uniform. 18-sigma separation at threshold 128.
__device__ int detect_bf16(const u32* __restrict__ x) {
    int c = 0;
#pragma unroll 8
    for (int i = 0; i < 256; ++i) {
        u32 e = (x[i] >> 7) & 0xFF;
        c += (e >= 100 && e <= 140) ? 1 : 0;
    }
    return c >= 128;
}

// Prologue: if x is fp32 and ws has room, pre-convert x -> bf16 once.
extern "C" __global__ void __launch_bounds__(256)
cvt_x_kernel(const void* __restrict__ x, u16* __restrict__ xb, int n4)
{
    __shared__ int flg;
    if (threadIdx.x == 0) flg = detect_bf16((const u32*)x);
    __syncthreads();
    if (flg) return;
    const float4* xf = (const float4*)x;
    u16x4* xo = (u16x4*)xb;
    for (int i = blockIdx.x * blockDim.x + threadIdx.x; i < n4;
         i += gridDim.x * blockDim.x) {
        float4 v = xf[i];
        u16x4 o;
        o[0] = (u16)bfb(v.x); o[1] = (u16)bfb(v.y);
        o[2] = (u16)bfb(v.z); o[3] = (u16)bfb(v.w);
        xo[i] = o;
    }
}

union Frag16 { u64 q[2]; short8 s8[1]; };

extern "C" __global__ void __launch_bounds__(NTHR)
lstm_persistent(const void* __restrict__ x,
                const void* __restrict__ Wxf, const void* __restrict__ Wxi,
                const void* __restrict__ Wxg, const void* __restrict__ Wxo,
                const void* __restrict__ Whf, const void* __restrict__ Whi,
                const void* __restrict__ Whg, const void* __restrict__ Who,
                const void* __restrict__ bxf, const void* __restrict__ bxi,
                const void* __restrict__ bxg, const void* __restrict__ bxo,
                const void* __restrict__ bhf, const void* __restrict__ bhi,
                const void* __restrict__ bhg, const void* __restrict__ bho,
                u16* __restrict__ h0buf, u16* __restrict__ h1buf,
                u16* __restrict__ xb, int* __restrict__ flags,
                void* __restrict__ outv)
{
    extern __shared__ char smem[];
    u16*   w_lds = (u16*)smem;
    float* g_lds = (float*)(smem + G_OFF);
    float* c_lds = (float*)(smem + C_OFF);
    float* b_lds = (float*)(smem + B_OFF);
    int*   f_lds = (int*)(smem + F_OFF);

    const int tid = threadIdx.x;
    const int blk = blockIdx.x;

    if (tid == 0) f_lds[0] = detect_bf16((const u32*)x);
    __syncthreads();
    const int bf16mode = f_lds[0];

    // ---- Stage weight slice once (bf16): cols [8*blk, 8*blk+8) of gates f,i,g,o.
    {
        const int gate = tid >> 6;   // wave-uniform
        const int kb   = tid & 63;
        const void* WX[4] = {Wxf, Wxi, Wxg, Wxo};
        const void* WH[4] = {Whf, Whi, Whg, Who};
        for (int it = 0; it < 16; ++it) {
            int k = it * 64 + kb;
            u16 vx[8], vh[8];
            if (bf16mode) {
                short8 a = *(const short8*)((const u16*)WX[gate] + (size_t)k * HD + blk * 8);
                short8 b = *(const short8*)((const u16*)WH[gate] + (size_t)k * HD + blk * 8);
#pragma unroll
                for (int ci = 0; ci < 8; ++ci) { vx[ci] = (u16)a[ci]; vh[ci] = (u16)b[ci]; }
            } else {
                const float* px = (const float*)WX[gate] + (size_t)k * HD + blk * 8;
                const float* ph = (const float*)WH[gate] + (size_t)k * HD + blk * 8;
                float4 a0 = *(const float4*)px, a1 = *(const float4*)(px + 4);
                float4 b0 = *(const float4*)ph, b1 = *(const float4*)(ph + 4);
                vx[0]=(u16)bfb(a0.x); vx[1]=(u16)bfb(a0.y); vx[2]=(u16)bfb(a0.z); vx[3]=(u16)bfb(a0.w);
                vx[4]=(u16)bfb(a1.x); vx[5]=(u16)bfb(a1.y); vx[6]=(u16)bfb(a1.z); vx[7]=(u16)bfb(a1.w);
                vh[0]=(u16)bfb(b0.x); vh[1]=(u16)bfb(b0.y); vh[2]=(u16)bfb(b0.z); vh[3]=(u16)bfb(b0.w);
                vh[4]=(u16)bfb(b1.x); vh[5]=(u16)bfb(b1.y); vh[6]=(u16)bfb(b1.z); vh[7]=(u16)bfb(b1.w);
            }
#pragma unroll
            for (int ci = 0; ci < 8; ++ci) {
                w_lds[(gate * 8 + ci) * WKS + k]        = vx[ci];
                w_lds[(gate * 8 + ci) * WKS + 1024 + k] = vh[ci];
            }
        }
    }
    for (int i = tid; i < BATCH * 8; i += NTHR) c_lds[i] = 0.f;   // c0 = 0
    if (tid < NCOL) {
        const void* BX[4] = {bxf, bxi, bxg, bxo};
        const void* BH[4] = {bhf, bhi, bhg, bho};
        int gate = tid >> 3, hc = blk * 8 + (tid & 7);
        float v;
        if (bf16mode)
            v = __bfloat162float(((const __hip_bfloat16*)BX[gate])[hc]) +
                __bfloat162float(((const __hip_bfloat16*)BH[gate])[hc]);
        else
            v = ((const float*)BX[gate])[hc] + ((const float*)BH[gate])[hc];
        b_lds[tid] = v;
    }
    __syncthreads();

    // MFMA 16x16x32 bf16: A[m=lane&15][k=quad*8+j], B[k=quad*8+j][n=lane&15],
    // C/D: col=lane&15, row=quad*4+reg.
    const int wv   = tid >> 6;
    const int lane = tid & 63;
    const int c16  = lane & 15;
    const int quad = lane >> 4;
    const int arow = wv * 16 + c16;

    const int use16 = bf16mode || (xb != nullptr);
    const u16*   x16l = nullptr;
    const float* xf_l = nullptr;
    if (use16) {
        const u16* x16 = bf16mode ? (const u16*)x : xb;
        x16l = x16 + (size_t)arow * T_STEPS * HD + quad * 8;
    } else {
        xf_l = (const float*)x + (size_t)arow * T_STEPS * HD + quad * 8;
    }
    const u16* wb0 = w_lds + c16 * WKS + quad * 8;         // N-subtile 0: cols 0-15
    const u16* wb1 = w_lds + (16 + c16) * WKS + quad * 8;  // N-subtile 1: cols 16-31

    const int r   = tid >> 2;        // gate-phase batch row
    const int hl0 = (tid & 3) * 2;   // gate-phase h-cols hl0, hl0+1 (adjacent -> u32 pack)

    u16* hbufs[2] = {h0buf, h1buf};
    int p = 0;
    const int polll = tid & 63;

    // x-side partials for t=0 (h-independent)
    f32x4 ax0 = {0.f,0.f,0.f,0.f}, ax1 = {0.f,0.f,0.f,0.f};
    {
        if (use16) {
            const u16* xp = x16l;
#pragma unroll 8
            for (int kc = 0; kc < 32; ++kc) {
                short8 a  = *(const short8*)(xp + kc * 32);
                short8 b0 = *(const short8*)(wb0 + kc * 32);
                short8 b1 = *(const short8*)(wb1 + kc * 32);
                ax0 = __builtin_amdgcn_mfma_f32_16x16x32_bf16(a, b0, ax0, 0, 0, 0);
                ax1 = __builtin_amdgcn_mfma_f32_16x16x32_bf16(a, b1, ax1, 0, 0, 0);
            }
        } else {
            const float* xp = xf_l;
#pragma unroll 4
            for (int kc = 0; kc < 32; ++kc) {
                float4 fa = *(const float4*)(xp + kc * 32);
                float4 fb = *(const float4*)(xp + kc * 32 + 4);
                short8 a = {bfb(fa.x), bfb(fa.y), bfb(fa.z), bfb(fa.w),
                            bfb(fb.x), bfb(fb.y), bfb(fb.z), bfb(fb.w)};
                short8 b0 = *(const short8*)(wb0 + kc * 32);
                short8 b1 = *(const short8*)(wb1 + kc * 32);
                ax0 = __builtin_amdgcn_mfma_f32_16x16x32_bf16(a, b0, ax0, 0, 0, 0);
                ax1 = __builtin_amdgcn_mfma_f32_16x16x32_bf16(a, b1, ax1, 0, 0, 0);
            }
        }
    }

    for (int t = 0; t < T_STEPS; ++t) {
        f32x4 a0 = ax0, a1 = ax1;

        if (t > 0) {
            // ---- flag barrier: parallel relaxed loads, no RMW, no cache ops.
            while (true) {
                int fa = __hip_atomic_load(&flags[polll], __ATOMIC_RELAXED,
                                           __HIP_MEMORY_SCOPE_AGENT);
                int fb = __hip_atomic_load(&flags[64 + polll], __ATOMIC_RELAXED,
                                           __HIP_MEMORY_SCOPE_AGENT);
                if (__all(fa >= t && fb >= t)) break;
                __builtin_amdgcn_s_sleep(1);
            }
            asm volatile("" ::: "memory");   // pin h-loads after poll break

            // ---- h-side K: 1024. Loads bypass L1/L2 (agent-scope atomic u64)
            //      and read the coherence point directly -> no buffer_inv needed.
            const u16* hp = hbufs[p] + (size_t)arow * HD + quad * 8;
#pragma unroll 8
            for (int kc = 0; kc < 32; ++kc) {
                Frag16 f;
                f.q[0] = __hip_atomic_load((const u64*)(hp + kc * 32),
                                           __ATOMIC_RELAXED, __HIP_MEMORY_SCOPE_AGENT);
                f.q[1] = __hip_atomic_load((const u64*)(hp + kc * 32 + 4),
                                           __ATOMIC_RELAXED, __HIP_MEMORY_SCOPE_AGENT);
                short8 a  = f.s8[0];
                short8 b0 = *(const short8*)(wb0 + 1024 + kc * 32);
                short8 b1 = *(const short8*)(wb1 + 1024 + kc * 32);
                a0 = __builtin_amdgcn_mfma_f32_16x16x32_bf16(a, b0, a0, 0, 0, 0);
                a1 = __builtin_amdgcn_mfma_f32_16x16x32_bf16(a, b1, a1, 0, 0, 0);
            }
        }

        // dump g to LDS
        const int rr = wv * 16 + quad * 4;
#pragma unroll
        for (int i2 = 0; i2 < 4; ++i2) {
            g_lds[(rr + i2) * G_STRIDE + c16]      = a0[i2];
            g_lds[(rr + i2) * G_STRIDE + 16 + c16] = a1[i2];
        }
        __syncthreads();

        // gate phase: thread handles (row r, adjacent local h-cols hl0, hl0+1)
        float hv[2]; float cv[2];
#pragma unroll
        for (int jj = 0; jj < 2; ++jj) {
            int hl = hl0 + jj;
            float gf = g_lds[r * G_STRIDE + hl]      + b_lds[hl];
            float gi = g_lds[r * G_STRIDE + 8 + hl]  + b_lds[8 + hl];
            float gg = g_lds[r * G_STRIDE + 16 + hl] + b_lds[16 + hl];
            float go = g_lds[r * G_STRIDE + 24 + hl] + b_lds[24 + hl];
            float fg = sigm(gf), ig = sigm(gi), og = sigm(go);
            float gt = tanh_(gg);
            float cnew = fg * c_lds[r * 8 + hl] + ig * gt;
            c_lds[r * 8 + hl] = cnew;
            cv[jj] = cnew;
            hv[jj] = tanh_(cnew) * og;
        }

        if (t < T_STEPS - 1) {
            // h store: write-through u32 (2 bf16) straight to coherence point.
            u32 pk = (u32)(u16)bfb(hv[0]) | ((u32)(u16)bfb(hv[1]) << 16);
            u16* hn = hbufs[p ^ 1];
            __hip_atomic_store((u32*)(hn + (size_t)r * HD + blk * 8 + hl0), pk,
                               __ATOMIC_RELAXED, __HIP_MEMORY_SCOPE_AGENT);
            // syncthreads drains all waves' vmcnt (write-through stores retire at
            // the coherence point) + separates g_lds WAR. No wbl2 needed.
            __syncthreads();
            if (tid == 0)
                __hip_atomic_store(&flags[blk], t + 1, __ATOMIC_RELAXED,
                                   __HIP_MEMORY_SCOPE_AGENT);
            p ^= 1;

            // ---- x-side partials for t+1: overlaps flag propagation + consumers
            ax0 = (f32x4){0.f,0.f,0.f,0.f};
            ax1 = (f32x4){0.f,0.f,0.f,0.f};
            if (use16) {
                const u16* xp = x16l + (size_t)(t + 1) * HD;
#pragma unroll 8
                for (int kc = 0; kc < 32; ++kc) {
                    short8 a  = *(const short8*)(xp + kc * 32);
                    short8 b0 = *(const short8*)(wb0 + kc * 32);
                    short8 b1 = *(const short8*)(wb1 + kc * 32);
                    ax0 = __builtin_amdgcn_mfma_f32_16x16x32_bf16(a, b0, ax0, 0, 0, 0);
                    ax1 = __builtin_amdgcn_mfma_f32_16x16x32_bf16(a, b1, ax1, 0, 0, 0);
                }
            } else {
                const float* xp = xf_l + (size_t)(t + 1) * HD;
#pragma unroll 4
                for (int kc = 0; kc < 32; ++kc) {
                    float4 fa = *(const float4*)(xp + kc * 32);
                    float4 fb = *(const float4*)(xp + kc * 32 + 4);
                    short8 a = {bfb(fa.x), bfb(fa.y), bfb(fa.z), bfb(fa.w),
                                bfb(fb.x), bfb(fb.y), bfb(fb.z), bfb(fb.w)};
                    short8 b0 = *(const short8*)(wb0 + kc * 32);
                    short8 b1 = *(const short8*)(wb1 + kc * 32);
                    ax0 = __builtin_amdgcn_mfma_f32_16x16x32_bf16(a, b0, ax0, 0, 0, 0);
                    ax1 = __builtin_amdgcn_mfma_f32_16x16x32_bf16(a, b1, ax1, 0, 0, 0);
                }
            }
        } else {
            // final step: write h_T and c_T (plain stores; kernel end flushes)
#pragma unroll
            for (int jj = 0; jj < 2; ++jj) {
                size_t idx = (size_t)r * HD + blk * 8 + hl0 + jj;
                if (bf16mode) {
                    u16* o = (u16*)outv;
                    __hip_bfloat16 hb = __float2bfloat16(hv[jj]);
                    __hip_bfloat16 cb = __float2bfloat16(cv[jj]);
                    o[idx] = *(u16*)&hb;
                    o[(size_t)BATCH * HD + idx] = *(u16*)&cb;
                } else {
                    float* o = (float*)outv;
                    o[idx] = hv[jj];
                    o[(size_t)BATCH * HD + idx] = cv[jj];
                }
            }
        }
    }
}

extern "C" void kernel_launch(void* const* d_in, const int* in_sizes, int n_in,
                              void* d_out, int out_size, void* d_ws, size_t ws_size,
                              hipStream_t stream) {
    (void)in_sizes; (void)n_in; (void)out_size;
    const void* x   = d_in[0];
    const void* Wii = d_in[1];  const void* Whi = d_in[2];
    const void* Wif = d_in[3];  const void* Whf = d_in[4];
    const void* Wig = d_in[5];  const void* Whg = d_in[6];
    const void* Wio = d_in[7];  const void* Who = d_in[8];
    const void* bii = d_in[9];  const void* bhi = d_in[10];
    const void* bif = d_in[11]; const void* bhf = d_in[12];
    const void* big = d_in[13]; const void* bhg = d_in[14];
    const void* bio = d_in[15]; const void* bho = d_in[16];

    int* flags = (int*)d_ws;                        // 128 flags (512 B), memset 0
    u16* h0 = (u16*)((char*)d_ws + 1024);           // 128 KB
    u16* h1 = h0 + BATCH * HD;                      // 128 KB
    size_t xb_off = 1024 + (size_t)2 * BATCH * HD * 2;            // 263168
    size_t need   = xb_off + (size_t)BATCH * T_STEPS * HD * 2;    // ~67.4 MB
    u16* xb = (ws_size >= need) ? (u16*)((char*)d_ws + xb_off) : nullptr;

    hipMemsetAsync(d_ws, 0, 1024, stream);
    if (xb)
        hipLaunchKernelGGL(cvt_x_kernel, dim3(2048), dim3(256), 0, stream,
                           x, xb, (BATCH * T_STEPS * HD) / 4);

    hipFuncSetAttribute((const void*)lstm_persistent,
                        hipFuncAttributeMaxDynamicSharedMemorySize, SMEM_BYTES);
    hipLaunchKernelGGL(lstm_persistent, dim3(NBLK), dim3(NTHR), SMEM_BYTES, stream,
                       x, Wif, Wii, Wig, Wio, Whf, Whi, Whg, Who,
                       bif, bii, big, bio, bhf, bhi, bhg, bho,
                       h0, h1, xb, flags, d_out);
}

// Round 5
// 7309.019 us; speedup vs baseline: 2.0570x; 1.0132x over previous
//
#include <hip/hip_runtime.h>
#include <hip/hip_bf16.h>

typedef unsigned short u16;
typedef unsigned int   u32;
typedef unsigned long long u64;
typedef short short8 __attribute__((ext_vector_type(8)));
typedef float f32x4  __attribute__((ext_vector_type(4)));
typedef u16   u16x4  __attribute__((ext_vector_type(4)));

#define T_STEPS 512
#define BATCH   64
#define HD      1024
#define NBLK    128    // 32 gate-cols per block, 1 block/CU (LDS-bound)
#define NTHR    256
#define NCOL    32
#define WKS     2056   // K-stride in LDS elems: 2048 + 8 pad (16B-aligned)

// LDS layout (bytes). c-state now lives in registers (wave-private rows).
#define W_BYTES    (NCOL * WKS * 2)       // 131584
#define G_OFF      W_BYTES
#define G_STRIDE   33
#define G_BYTES    (BATCH * G_STRIDE * 4) // 8448
#define B_OFF      (G_OFF + G_BYTES)
#define B_BYTES    (NCOL * 4)             // 128
#define F_OFF      (B_OFF + B_BYTES)
#define SMEM_BYTES (F_OFF + 16)           // ~140 KB < 160 KB -> 1 block/CU

__device__ __forceinline__ float sigm(float x) { return 1.f / (1.f + __expf(-x)); }
__device__ __forceinline__ float tanh_(float x) {
    float ax = __builtin_fabsf(x);
    float e  = __expf(-2.f * ax);
    float r  = (1.f - e) / (1.f + e);
    return x < 0.f ? -r : r;
}
__device__ __forceinline__ short bfb(float f) {          // fp32 -> bf16 bits (RNE)
    __hip_bfloat16 h = __float2bfloat16(f);
    return *(short*)&h;
}

// Dtype probe: packed-bf16 x -> low-u16 exponent in [100,140] ~always;
// fp32 x -> mantissa junk, ~uniform. 18-sigma separation at threshold 128.
__device__ int detect_bf16(const u32* __restrict__ x) {
    int c = 0;
#pragma unroll 8
    for (int i = 0; i < 256; ++i) {
        u32 e = (x[i] >> 7) & 0xFF;
        c += (e >= 100 && e <= 140) ? 1 : 0;
    }
    return c >= 128;
}

// Prologue: if x is fp32 and ws has room, pre-convert x -> bf16 once.
extern "C" __global__ void __launch_bounds__(256)
cvt_x_kernel(const void* __restrict__ x, u16* __restrict__ xb, int n4)
{
    __shared__ int flg;
    if (threadIdx.x == 0) flg = detect_bf16((const u32*)x);
    __syncthreads();
    if (flg) return;
    const float4* xf = (const float4*)x;
    u16x4* xo = (u16x4*)xb;
    for (int i = blockIdx.x * blockDim.x + threadIdx.x; i < n4;
         i += gridDim.x * blockDim.x) {
        float4 v = xf[i];
        u16x4 o;
        o[0] = (u16)bfb(v.x); o[1] = (u16)bfb(v.y);
        o[2] = (u16)bfb(v.z); o[3] = (u16)bfb(v.w);
        xo[i] = o;
    }
}

union Frag16 { u64 q[2]; short8 s8[1]; };

// Load one K-chunk (4 MFMA-iters, 128 K-cols) of h for this lane's A-row.
// Agent-scope u64 loads bypass L1/L2 -> read L3 (coherence point) directly.
__device__ __forceinline__ void load_chunk(const u16* hp, int c, Frag16* buf) {
#pragma unroll
    for (int it = 0; it < 4; ++it) {
        const u16* ptr = hp + c * 128 + it * 32;
        buf[it].q[0] = __hip_atomic_load((const u64*)ptr, __ATOMIC_RELAXED,
                                         __HIP_MEMORY_SCOPE_AGENT);
        buf[it].q[1] = __hip_atomic_load((const u64*)(ptr + 4), __ATOMIC_RELAXED,
                                         __HIP_MEMORY_SCOPE_AGENT);
    }
}

// Spin until all 16 producer-wave flags of chunk c (row-class wv) reach t.
__device__ __forceinline__ void poll_chunk(const int* flags, int c, int wv,
                                           int t, int lane) {
    const int idx = 64 * c + 4 * (lane & 15) + wv;
    while (true) {
        int f = __hip_atomic_load(&flags[idx], __ATOMIC_RELAXED,
                                  __HIP_MEMORY_SCOPE_AGENT);
        if (__all(f >= t)) break;
        __builtin_amdgcn_s_sleep(1);
    }
}

extern "C" __global__ void __launch_bounds__(NTHR)
lstm_persistent(const void* __restrict__ x,
                const void* __restrict__ Wxf, const void* __restrict__ Wxi,
                const void* __restrict__ Wxg, const void* __restrict__ Wxo,
                const void* __restrict__ Whf, const void* __restrict__ Whi,
                const void* __restrict__ Whg, const void* __restrict__ Who,
                const void* __restrict__ bxf, const void* __restrict__ bxi,
                const void* __restrict__ bxg, const void* __restrict__ bxo,
                const void* __restrict__ bhf, const void* __restrict__ bhi,
                const void* __restrict__ bhg, const void* __restrict__ bho,
                u16* __restrict__ h0buf, u16* __restrict__ h1buf,
                u16* __restrict__ xb, int* __restrict__ flags,
                void* __restrict__ outv)
{
    extern __shared__ char smem[];
    u16*   w_lds = (u16*)smem;
    float* g_lds = (float*)(smem + G_OFF);
    float* b_lds = (float*)(smem + B_OFF);
    int*   f_lds = (int*)(smem + F_OFF);

    const int tid = threadIdx.x;
    const int blk = blockIdx.x;

    if (tid == 0) f_lds[0] = detect_bf16((const u32*)x);
    __syncthreads();
    const int bf16mode = f_lds[0];

    // ---- Stage weight slice once (bf16): cols [8*blk, 8*blk+8) of gates f,i,g,o.
    //      LDS: [gate-col][K], K = 1024 x-side then 1024 h-side, k-contiguous.
    {
        const int gate = tid >> 6;   // wave-uniform
        const int kb   = tid & 63;
        const void* WX[4] = {Wxf, Wxi, Wxg, Wxo};
        const void* WH[4] = {Whf, Whi, Whg, Who};
        for (int it = 0; it < 16; ++it) {
            int k = it * 64 + kb;
            u16 vx[8], vh[8];
            if (bf16mode) {
                short8 a = *(const short8*)((const u16*)WX[gate] + (size_t)k * HD + blk * 8);
                short8 b = *(const short8*)((const u16*)WH[gate] + (size_t)k * HD + blk * 8);
#pragma unroll
                for (int ci = 0; ci < 8; ++ci) { vx[ci] = (u16)a[ci]; vh[ci] = (u16)b[ci]; }
            } else {
                const float* px = (const float*)WX[gate] + (size_t)k * HD + blk * 8;
                const float* ph = (const float*)WH[gate] + (size_t)k * HD + blk * 8;
                float4 a0 = *(const float4*)px, a1 = *(const float4*)(px + 4);
                float4 b0 = *(const float4*)ph, b1 = *(const float4*)(ph + 4);
                vx[0]=(u16)bfb(a0.x); vx[1]=(u16)bfb(a0.y); vx[2]=(u16)bfb(a0.z); vx[3]=(u16)bfb(a0.w);
                vx[4]=(u16)bfb(a1.x); vx[5]=(u16)bfb(a1.y); vx[6]=(u16)bfb(a1.z); vx[7]=(u16)bfb(a1.w);
                vh[0]=(u16)bfb(b0.x); vh[1]=(u16)bfb(b0.y); vh[2]=(u16)bfb(b0.z); vh[3]=(u16)bfb(b0.w);
                vh[4]=(u16)bfb(b1.x); vh[5]=(u16)bfb(b1.y); vh[6]=(u16)bfb(b1.z); vh[7]=(u16)bfb(b1.w);
            }
#pragma unroll
            for (int ci = 0; ci < 8; ++ci) {
                w_lds[(gate * 8 + ci) * WKS + k]        = vx[ci];
                w_lds[(gate * 8 + ci) * WKS + 1024 + k] = vh[ci];
            }
        }
    }
    if (tid < NCOL) {
        const void* BX[4] = {bxf, bxi, bxg, bxo};
        const void* BH[4] = {bhf, bhi, bhg, bho};
        int gate = tid >> 3, hc = blk * 8 + (tid & 7);
        float v;
        if (bf16mode)
            v = __bfloat162float(((const __hip_bfloat16*)BX[gate])[hc]) +
                __bfloat162float(((const __hip_bfloat16*)BH[gate])[hc]);
        else
            v = ((const float*)BX[gate])[hc] + ((const float*)BH[gate])[hc];
        b_lds[tid] = v;
    }
    __syncthreads();   // last block-wide sync: w_lds/b_lds now read-only

    // MFMA 16x16x32 bf16: A[m=lane&15][k=quad*8+j], B[k=quad*8+j][n=lane&15],
    // C/D: col=lane&15, row=quad*4+reg  [m89/m91].
    const int wv   = tid >> 6;       // wave = row-class (16 batch rows) -- fully
    const int lane = tid & 63;       // independent pipeline, no intra-block sync
    const int c16  = lane & 15;
    const int quad = lane >> 4;
    const int arow = wv * 16 + c16;  // batch row this lane loads for A

    const int use16 = bf16mode || (xb != nullptr);
    const u16*   x16l = nullptr;
    const float* xf_l = nullptr;
    if (use16) {
        const u16* x16 = bf16mode ? (const u16*)x : xb;
        x16l = x16 + (size_t)arow * T_STEPS * HD + quad * 8;
    } else {
        xf_l = (const float*)x + (size_t)arow * T_STEPS * HD + quad * 8;
    }
    const u16* wb0 = w_lds + c16 * WKS + quad * 8;         // N-subtile 0: cols 0-15
    const u16* wb1 = w_lds + (16 + c16) * WKS + quad * 8;  // N-subtile 1: cols 16-31

    // gate-phase mapping (wave-private rows): row = wv*16 + (lane>>2),
    // two adjacent local h-cols hl0, hl0+1.
    const int grow = wv * 16 + (lane >> 2);
    const int hl0  = (lane & 3) * 2;
    float bias[8];
#pragma unroll
    for (int g = 0; g < 4; ++g) {
        bias[g * 2]     = b_lds[g * 8 + hl0];
        bias[g * 2 + 1] = b_lds[g * 8 + hl0 + 1];
    }
    float creg[2] = {0.f, 0.f};      // c-state lives in registers (c0 = 0)

    u16* hbufs[2] = {h0buf, h1buf};
    int p = 0;
    const int c0 = blk >> 4;         // own chunk first (own flag self-set)

    // x-side partials for t=0 (h-independent)
    f32x4 ax0 = {0.f,0.f,0.f,0.f}, ax1 = {0.f,0.f,0.f,0.f};
    if (use16) {
        const u16* xp = x16l;
#pragma unroll 8
        for (int kc = 0; kc < 32; ++kc) {
            short8 a  = *(const short8*)(xp + kc * 32);
            short8 b0 = *(const short8*)(wb0 + kc * 32);
            short8 b1 = *(const short8*)(wb1 + kc * 32);
            ax0 = __builtin_amdgcn_mfma_f32_16x16x32_bf16(a, b0, ax0, 0, 0, 0);
            ax1 = __builtin_amdgcn_mfma_f32_16x16x32_bf16(a, b1, ax1, 0, 0, 0);
        }
    } else {
        const float* xp = xf_l;
#pragma unroll 4
        for (int kc = 0; kc < 32; ++kc) {
            float4 fa = *(const float4*)(xp + kc * 32);
            float4 fb = *(const float4*)(xp + kc * 32 + 4);
            short8 a = {bfb(fa.x), bfb(fa.y), bfb(fa.z), bfb(fa.w),
                        bfb(fb.x), bfb(fb.y), bfb(fb.z), bfb(fb.w)};
            short8 b0 = *(const short8*)(wb0 + kc * 32);
            short8 b1 = *(const short8*)(wb1 + kc * 32);
            ax0 = __builtin_amdgcn_mfma_f32_16x16x32_bf16(a, b0, ax0, 0, 0, 0);
            ax1 = __builtin_amdgcn_mfma_f32_16x16x32_bf16(a, b1, ax1, 0, 0, 0);
        }
    }

    for (int t = 0; t < T_STEPS; ++t) {
        f32x4 a0 = ax0, a1 = ax1;

        if (t > 0) {
            const u16* hp = hbufs[p] + (size_t)arow * HD + quad * 8;

            // ---- one flag sweep gives all 8 chunk-ready bits (2 loads + ballots)
            int f1 = __hip_atomic_load(&flags[4 * lane + wv], __ATOMIC_RELAXED,
                                       __HIP_MEMORY_SCOPE_AGENT);
            int f2 = __hip_atomic_load(&flags[256 + 4 * lane + wv], __ATOMIC_RELAXED,
                                       __HIP_MEMORY_SCOPE_AGENT);
            u64 m1 = __ballot(f1 >= t);
            u64 m2 = __ballot(f2 >= t);

            Frag16 bufA[4], bufB[4];
            {
                u64 m = (c0 < 4) ? (m1 >> (16 * c0)) : (m2 >> (16 * (c0 - 4)));
                if ((m & 0xFFFFull) != 0xFFFFull) poll_chunk(flags, c0, wv, t, lane);
            }
            load_chunk(hp, c0, bufA);

            // ---- 2-deep chunk pipeline: poll+load chunk ci+1 while MFMAing ci
#pragma unroll
            for (int ci = 0; ci < 8; ++ci) {
                const int cc = (c0 + ci) & 7;
                Frag16* cur = (ci & 1) ? bufB : bufA;
                Frag16* nxt = (ci & 1) ? bufA : bufB;
                if (ci < 7) {
                    const int cn = (c0 + ci + 1) & 7;
                    u64 m = (cn < 4) ? (m1 >> (16 * cn)) : (m2 >> (16 * (cn - 4)));
                    if ((m & 0xFFFFull) != 0xFFFFull) poll_chunk(flags, cn, wv, t, lane);
                    load_chunk(hp, cn, nxt);
                }
#pragma unroll
                for (int it = 0; it < 4; ++it) {
                    short8 a  = cur[it].s8[0];
                    short8 b0 = *(const short8*)(wb0 + 1024 + cc * 128 + it * 32);
                    short8 b1 = *(const short8*)(wb1 + 1024 + cc * 128 + it * 32);
                    a0 = __builtin_amdgcn_mfma_f32_16x16x32_bf16(a, b0, a0, 0, 0, 0);
                    a1 = __builtin_amdgcn_mfma_f32_16x16x32_bf16(a, b1, a1, 0, 0, 0);
                }
            }
        }

        // ---- dump g to wave-private LDS rows (no cross-wave traffic)
        const int rr = wv * 16 + quad * 4;
#pragma unroll
        for (int i2 = 0; i2 < 4; ++i2) {
            g_lds[(rr + i2) * G_STRIDE + c16]      = a0[i2];
            g_lds[(rr + i2) * G_STRIDE + 16 + c16] = a1[i2];
        }
        asm volatile("s_waitcnt lgkmcnt(0)" ::: "memory");  // wave-internal LDS order

        // ---- gates: wave-local; c-state in registers
        float hv[2], cv[2];
#pragma unroll
        for (int jj = 0; jj < 2; ++jj) {
            int hl = hl0 + jj;
            float gf = g_lds[grow * G_STRIDE + hl]      + bias[jj];
            float gi = g_lds[grow * G_STRIDE + 8 + hl]  + bias[2 + jj];
            float gg = g_lds[grow * G_STRIDE + 16 + hl] + bias[4 + jj];
            float go = g_lds[grow * G_STRIDE + 24 + hl] + bias[6 + jj];
            float fg = sigm(gf), ig = sigm(gi), og = sigm(go);
            float gt = tanh_(gg);
            float cnew = fg * creg[jj] + ig * gt;
            creg[jj] = cnew;
            cv[jj] = cnew;
            hv[jj] = tanh_(cnew) * og;
        }

        if (t < T_STEPS - 1) {
            // h store: write-through u32 (2 bf16) straight to coherence point.
            u32 pk = (u32)(u16)bfb(hv[0]) | ((u32)(u16)bfb(hv[1]) << 16);
            u16* hn = hbufs[p ^ 1];
            __hip_atomic_store((u32*)(hn + (size_t)grow * HD + blk * 8 + hl0), pk,
                               __ATOMIC_RELAXED, __HIP_MEMORY_SCOPE_AGENT);
            // wave-local release: drain own vm ops, then publish per-wave flag.
            asm volatile("s_waitcnt vmcnt(0)" ::: "memory");
            if (lane == 0)
                __hip_atomic_store(&flags[4 * blk + wv], t + 1, __ATOMIC_RELAXED,
                                   __HIP_MEMORY_SCOPE_AGENT);
            p ^= 1;

            // ---- x-side partials for t+1 (fills the flag-propagation window)
            ax0 = (f32x4){0.f,0.f,0.f,0.f};
            ax1 = (f32x4){0.f,0.f,0.f,0.f};
            if (use16) {
                const u16* xp = x16l + (size_t)(t + 1) * HD;
#pragma unroll 8
                for (int kc = 0; kc < 32; ++kc) {
                    short8 a  = *(const short8*)(xp + kc * 32);
                    short8 b0 = *(const short8*)(wb0 + kc * 32);
                    short8 b1 = *(const short8*)(wb1 + kc * 32);
                    ax0 = __builtin_amdgcn_mfma_f32_16x16x32_bf16(a, b0, ax0, 0, 0, 0);
                    ax1 = __builtin_amdgcn_mfma_f32_16x16x32_bf16(a, b1, ax1, 0, 0, 0);
                }
            } else {
                const float* xp = xf_l + (size_t)(t + 1) * HD;
#pragma unroll 4
                for (int kc = 0; kc < 32; ++kc) {
                    float4 fa = *(const float4*)(xp + kc * 32);
                    float4 fb = *(const float4*)(xp + kc * 32 + 4);
                    short8 a = {bfb(fa.x), bfb(fa.y), bfb(fa.z), bfb(fa.w),
                                bfb(fb.x), bfb(fb.y), bfb(fb.z), bfb(fb.w)};
                    short8 b0 = *(const short8*)(wb0 + kc * 32);
                    short8 b1 = *(const short8*)(wb1 + kc * 32);
                    ax0 = __builtin_amdgcn_mfma_f32_16x16x32_bf16(a, b0, ax0, 0, 0, 0);
                    ax1 = __builtin_amdgcn_mfma_f32_16x16x32_bf16(a, b1, ax1, 0, 0, 0);
                }
            }
        } else {
            // final step: write h_T and c_T (wave-private rows)
#pragma unroll
            for (int jj = 0; jj < 2; ++jj) {
                size_t idx = (size_t)grow * HD + blk * 8 + hl0 + jj;
                if (bf16mode) {
                    u16* o = (u16*)outv;
                    __hip_bfloat16 hb = __float2bfloat16(hv[jj]);
                    __hip_bfloat16 cb = __float2bfloat16(cv[jj]);
                    o[idx] = *(u16*)&hb;
                    o[(size_t)BATCH * HD + idx] = *(u16*)&cb;
                } else {
                    float* o = (float*)outv;
                    o[idx] = hv[jj];
                    o[(size_t)BATCH * HD + idx] = cv[jj];
                }
            }
        }
    }
}

extern "C" void kernel_launch(void* const* d_in, const int* in_sizes, int n_in,
                              void* d_out, int out_size, void* d_ws, size_t ws_size,
                              hipStream_t stream) {
    (void)in_sizes; (void)n_in; (void)out_size;
    const void* x   = d_in[0];
    const void* Wii = d_in[1];  const void* Whi = d_in[2];
    const void* Wif = d_in[3];  const void* Whf = d_in[4];
    const void* Wig = d_in[5];  const void* Whg = d_in[6];
    const void* Wio = d_in[7];  const void* Who = d_in[8];
    const void* bii = d_in[9];  const void* bhi = d_in[10];
    const void* bif = d_in[11]; const void* bhf = d_in[12];
    const void* big = d_in[13]; const void* bhg = d_in[14];
    const void* bio = d_in[15]; const void* bho = d_in[16];

    int* flags = (int*)d_ws;                        // 512 per-wave flags (2 KB)
    u16* h0 = (u16*)((char*)d_ws + 4096);           // 128 KB
    u16* h1 = h0 + BATCH * HD;                      // 128 KB
    size_t xb_off = 4096 + (size_t)2 * BATCH * HD * 2;
    size_t need   = xb_off + (size_t)BATCH * T_STEPS * HD * 2;    // ~67.4 MB
    u16* xb = (ws_size >= need) ? (u16*)((char*)d_ws + xb_off) : nullptr;

    hipMemsetAsync(d_ws, 0, 4096, stream);
    if (xb)
        hipLaunchKernelGGL(cvt_x_kernel, dim3(2048), dim3(256), 0, stream,
                           x, xb, (BATCH * T_STEPS * HD) / 4);

    hipFuncSetAttribute((const void*)lstm_persistent,
                        hipFuncAttributeMaxDynamicSharedMemorySize, SMEM_BYTES);
    hipLaunchKernelGGL(lstm_persistent, dim3(NBLK), dim3(NTHR), SMEM_BYTES, stream,
                       x, Wif, Wii, Wig, Wio, Whf, Whi, Whg, Who,
                       bif, bii, big, bio, bhf, bhi, bhg, bho,
                       h0, h1, xb, flags, d_out);
}

// Round 6
// 5454.001 us; speedup vs baseline: 2.7566x; 1.3401x over previous
//
#include <hip/hip_runtime.h>
#include <hip/hip_bf16.h>

typedef unsigned short u16;
typedef unsigned int   u32;
typedef unsigned long long u64;
typedef short short8 __attribute__((ext_vector_type(8)));
typedef float f32x4  __attribute__((ext_vector_type(4)));
typedef u16   u16x4  __attribute__((ext_vector_type(4)));

#define T_STEPS 512
#define BATCH   64
#define HD      1024
#define NBLK    128    // 32 gate-cols per block, 1 block/CU (LDS-bound)
#define NTHR    256
#define NCOL    32
#define WKS     2056   // K-stride in LDS elems: 2048 + 8 pad (16B-aligned)
#define HBUF_E  (BATCH * HD)   // elems per h buffer (128 KB)

// LDS layout (bytes). c-state lives in registers (wave-private rows).
#define W_BYTES    (NCOL * WKS * 2)       // 131584
#define G_OFF      W_BYTES
#define G_STRIDE   33
#define G_BYTES    (BATCH * G_STRIDE * 4) // 8448
#define B_OFF      (G_OFF + G_BYTES)
#define B_BYTES    (NCOL * 4)             // 128
#define F_OFF      (B_OFF + B_BYTES)
#define SMEM_BYTES (F_OFF + 16)           // ~140 KB < 160 KB -> 1 block/CU

__device__ __forceinline__ float sigm(float x) { return 1.f / (1.f + __expf(-x)); }
__device__ __forceinline__ float tanh_(float x) {
    float ax = __builtin_fabsf(x);
    float e  = __expf(-2.f * ax);
    float r  = (1.f - e) / (1.f + e);
    return x < 0.f ? -r : r;
}
__device__ __forceinline__ short bfb(float f) {          // fp32 -> bf16 bits (RNE)
    __hip_bfloat16 h = __float2bfloat16(f);
    return *(short*)&h;
}

// Dtype probe: packed-bf16 x -> low-u16 exponent in [100,140] ~always;
// fp32 x -> mantissa junk, ~uniform. 18-sigma separation at threshold 128.
__device__ int detect_bf16(const u32* __restrict__ x) {
    int c = 0;
#pragma unroll 8
    for (int i = 0; i < 256; ++i) {
        u32 e = (x[i] >> 7) & 0xFF;
        c += (e >= 100 && e <= 140) ? 1 : 0;
    }
    return c >= 128;
}

// Prologue: if x is fp32 and ws has room, pre-convert x -> bf16 once.
extern "C" __global__ void __launch_bounds__(256)
cvt_x_kernel(const void* __restrict__ x, u16* __restrict__ xb, int n4)
{
    __shared__ int flg;
    if (threadIdx.x == 0) flg = detect_bf16((const u32*)x);
    __syncthreads();
    if (flg) return;
    const float4* xf = (const float4*)x;
    u16x4* xo = (u16x4*)xb;
    for (int i = blockIdx.x * blockDim.x + threadIdx.x; i < n4;
         i += gridDim.x * blockDim.x) {
        float4 v = xf[i];
        u16x4 o;
        o[0] = (u16)bfb(v.x); o[1] = (u16)bfb(v.y);
        o[2] = (u16)bfb(v.z); o[3] = (u16)bfb(v.w);
        xo[i] = o;
    }
}

union Frag16 { u64 q[2]; short8 s8[1]; };

// Load one K-chunk (4 MFMA-iters, 128 K-cols) of h for this lane's A-row.
// ring mode: plain cached 16-B loads (write-once ring buffer => L2/L1-cacheable;
//            per-XCD fill once, 15 other CUs hit L2). legacy: 8-B agent-scope
//            atomic loads straight from the coherence point.
__device__ __forceinline__ void load_chunk(const u16* hp, int c, Frag16* buf,
                                           int ring_on) {
    if (ring_on) {
#pragma unroll
        for (int it = 0; it < 4; ++it)
            buf[it].s8[0] = *(const short8*)(hp + c * 128 + it * 32);
    } else {
#pragma unroll
        for (int it = 0; it < 4; ++it) {
            const u16* ptr = hp + c * 128 + it * 32;
            buf[it].q[0] = __hip_atomic_load((const u64*)ptr, __ATOMIC_RELAXED,
                                             __HIP_MEMORY_SCOPE_AGENT);
            buf[it].q[1] = __hip_atomic_load((const u64*)(ptr + 4), __ATOMIC_RELAXED,
                                             __HIP_MEMORY_SCOPE_AGENT);
        }
    }
}

// Spin until all 16 producer-wave flags of chunk c (row-class wv) reach t.
// Compiler barrier at exit: h loads must not be speculated above the poll.
__device__ __forceinline__ void poll_chunk(const int* flags, int c, int wv,
                                           int t, int lane) {
    const int idx = 64 * c + 4 * (lane & 15) + wv;
    while (true) {
        int f = __hip_atomic_load(&flags[idx], __ATOMIC_RELAXED,
                                  __HIP_MEMORY_SCOPE_AGENT);
        if (__all(f >= t)) break;
        __builtin_amdgcn_s_sleep(1);
    }
    asm volatile("" ::: "memory");
}

extern "C" __global__ void __launch_bounds__(NTHR)
lstm_persistent(const void* __restrict__ x,
                const void* __restrict__ Wxf, const void* __restrict__ Wxi,
                const void* __restrict__ Wxg, const void* __restrict__ Wxo,
                const void* __restrict__ Whf, const void* __restrict__ Whi,
                const void* __restrict__ Whg, const void* __restrict__ Who,
                const void* __restrict__ bxf, const void* __restrict__ bxi,
                const void* __restrict__ bxg, const void* __restrict__ bxo,
                const void* __restrict__ bhf, const void* __restrict__ bhi,
                const void* __restrict__ bhg, const void* __restrict__ bho,
                u16* __restrict__ hring, int ring_on,
                u16* __restrict__ xb, int* __restrict__ flags,
                void* __restrict__ outv)
{
    // One-time agent acquire: buffer_inv clears L1/L2 of poison + prior-replay
    // ring lines. After this, ring lines enter caches only via demand misses
    // that happen after the producing flags were observed (fresh in L3).
    __builtin_amdgcn_fence(__ATOMIC_ACQUIRE, "agent");

    extern __shared__ char smem[];
    u16*   w_lds = (u16*)smem;
    float* g_lds = (float*)(smem + G_OFF);
    float* b_lds = (float*)(smem + B_OFF);
    int*   f_lds = (int*)(smem + F_OFF);

    const int tid = threadIdx.x;
    const int blk = blockIdx.x;

    if (tid == 0) f_lds[0] = detect_bf16((const u32*)x);
    __syncthreads();
    const int bf16mode = f_lds[0];

    // ---- Stage weight slice once (bf16): cols [8*blk, 8*blk+8) of gates f,i,g,o.
    //      LDS: [gate-col][K], K = 1024 x-side then 1024 h-side, k-contiguous.
    {
        const int gate = tid >> 6;   // wave-uniform
        const int kb   = tid & 63;
        const void* WX[4] = {Wxf, Wxi, Wxg, Wxo};
        const void* WH[4] = {Whf, Whi, Whg, Who};
        for (int it = 0; it < 16; ++it) {
            int k = it * 64 + kb;
            u16 vx[8], vh[8];
            if (bf16mode) {
                short8 a = *(const short8*)((const u16*)WX[gate] + (size_t)k * HD + blk * 8);
                short8 b = *(const short8*)((const u16*)WH[gate] + (size_t)k * HD + blk * 8);
#pragma unroll
                for (int ci = 0; ci < 8; ++ci) { vx[ci] = (u16)a[ci]; vh[ci] = (u16)b[ci]; }
            } else {
                const float* px = (const float*)WX[gate] + (size_t)k * HD + blk * 8;
                const float* ph = (const float*)WH[gate] + (size_t)k * HD + blk * 8;
                float4 a0 = *(const float4*)px, a1 = *(const float4*)(px + 4);
                float4 b0 = *(const float4*)ph, b1 = *(const float4*)(ph + 4);
                vx[0]=(u16)bfb(a0.x); vx[1]=(u16)bfb(a0.y); vx[2]=(u16)bfb(a0.z); vx[3]=(u16)bfb(a0.w);
                vx[4]=(u16)bfb(a1.x); vx[5]=(u16)bfb(a1.y); vx[6]=(u16)bfb(a1.z); vx[7]=(u16)bfb(a1.w);
                vh[0]=(u16)bfb(b0.x); vh[1]=(u16)bfb(b0.y); vh[2]=(u16)bfb(b0.z); vh[3]=(u16)bfb(b0.w);
                vh[4]=(u16)bfb(b1.x); vh[5]=(u16)bfb(b1.y); vh[6]=(u16)bfb(b1.z); vh[7]=(u16)bfb(b1.w);
            }
#pragma unroll
            for (int ci = 0; ci < 8; ++ci) {
                w_lds[(gate * 8 + ci) * WKS + k]        = vx[ci];
                w_lds[(gate * 8 + ci) * WKS + 1024 + k] = vh[ci];
            }
        }
    }
    if (tid < NCOL) {
        const void* BX[4] = {bxf, bxi, bxg, bxo};
        const void* BH[4] = {bhf, bhi, bhg, bho};
        int gate = tid >> 3, hc = blk * 8 + (tid & 7);
        float v;
        if (bf16mode)
            v = __bfloat162float(((const __hip_bfloat16*)BX[gate])[hc]) +
                __bfloat162float(((const __hip_bfloat16*)BH[gate])[hc]);
        else
            v = ((const float*)BX[gate])[hc] + ((const float*)BH[gate])[hc];
        b_lds[tid] = v;
    }
    __syncthreads();   // last block-wide sync: w_lds/b_lds now read-only

    // MFMA 16x16x32 bf16: A[m=lane&15][k=quad*8+j], B[k=quad*8+j][n=lane&15],
    // C/D: col=lane&15, row=quad*4+reg  [m89/m91].
    const int wv   = tid >> 6;       // wave = row-class (16 batch rows) -- fully
    const int lane = tid & 63;       // independent pipeline, no intra-block sync
    const int c16  = lane & 15;
    const int quad = lane >> 4;
    const int arow = wv * 16 + c16;  // batch row this lane loads for A

    const int use16 = bf16mode || (xb != nullptr);
    const u16*   x16l = nullptr;
    const float* xf_l = nullptr;
    if (use16) {
        const u16* x16 = bf16mode ? (const u16*)x : xb;
        x16l = x16 + (size_t)arow * T_STEPS * HD + quad * 8;
    } else {
        xf_l = (const float*)x + (size_t)arow * T_STEPS * HD + quad * 8;
    }
    const u16* wb0 = w_lds + c16 * WKS + quad * 8;         // N-subtile 0: cols 0-15
    const u16* wb1 = w_lds + (16 + c16) * WKS + quad * 8;  // N-subtile 1: cols 16-31

    // gate-phase mapping (wave-private rows): row = wv*16 + (lane>>2),
    // two adjacent local h-cols hl0, hl0+1.
    const int grow = wv * 16 + (lane >> 2);
    const int hl0  = (lane & 3) * 2;
    float bias[8];
#pragma unroll
    for (int g = 0; g < 4; ++g) {
        bias[g * 2]     = b_lds[g * 8 + hl0];
        bias[g * 2 + 1] = b_lds[g * 8 + hl0 + 1];
    }
    float creg[2] = {0.f, 0.f};      // c-state lives in registers (c0 = 0)

    const int c0 = blk >> 4;         // own chunk first (own flag self-set)

    // x-side partials for t=0 (h-independent)
    f32x4 ax0 = {0.f,0.f,0.f,0.f}, ax1 = {0.f,0.f,0.f,0.f};
    if (use16) {
        const u16* xp = x16l;
#pragma unroll 8
        for (int kc = 0; kc < 32; ++kc) {
            short8 a  = *(const short8*)(xp + kc * 32);
            short8 b0 = *(const short8*)(wb0 + kc * 32);
            short8 b1 = *(const short8*)(wb1 + kc * 32);
            ax0 = __builtin_amdgcn_mfma_f32_16x16x32_bf16(a, b0, ax0, 0, 0, 0);
            ax1 = __builtin_amdgcn_mfma_f32_16x16x32_bf16(a, b1, ax1, 0, 0, 0);
        }
    } else {
        const float* xp = xf_l;
#pragma unroll 4
        for (int kc = 0; kc < 32; ++kc) {
            float4 fa = *(const float4*)(xp + kc * 32);
            float4 fb = *(const float4*)(xp + kc * 32 + 4);
            short8 a = {bfb(fa.x), bfb(fa.y), bfb(fa.z), bfb(fa.w),
                        bfb(fb.x), bfb(fb.y), bfb(fb.z), bfb(fb.w)};
            short8 b0 = *(const short8*)(wb0 + kc * 32);
            short8 b1 = *(const short8*)(wb1 + kc * 32);
            ax0 = __builtin_amdgcn_mfma_f32_16x16x32_bf16(a, b0, ax0, 0, 0, 0);
            ax1 = __builtin_amdgcn_mfma_f32_16x16x32_bf16(a, b1, ax1, 0, 0, 0);
        }
    }

    for (int t = 0; t < T_STEPS; ++t) {
        f32x4 a0 = ax0, a1 = ax1;

        if (t > 0) {
            // h consumed at step t lives in buffer (t-1) [ring] / (t&1) [legacy]
            const u16* hp = hring + (size_t)(ring_on ? (t - 1) : (t & 1)) * HBUF_E
                          + (size_t)arow * HD + quad * 8;

            // ---- one flag sweep gives all 8 chunk-ready bits (2 loads + ballots)
            int f1 = __hip_atomic_load(&flags[4 * lane + wv], __ATOMIC_RELAXED,
                                       __HIP_MEMORY_SCOPE_AGENT);
            int f2 = __hip_atomic_load(&flags[256 + 4 * lane + wv], __ATOMIC_RELAXED,
                                       __HIP_MEMORY_SCOPE_AGENT);
            u64 m1 = __ballot(f1 >= t);
            u64 m2 = __ballot(f2 >= t);
            asm volatile("" ::: "memory");

            Frag16 bufA[4], bufB[4];
            {
                u64 m = (c0 < 4) ? (m1 >> (16 * c0)) : (m2 >> (16 * (c0 - 4)));
                if ((m & 0xFFFFull) != 0xFFFFull) poll_chunk(flags, c0, wv, t, lane);
            }
            load_chunk(hp, c0, bufA, ring_on);

            // ---- 2-deep chunk pipeline: poll+load chunk ci+1 while MFMAing ci
#pragma unroll
            for (int ci = 0; ci < 8; ++ci) {
                const int cc = (c0 + ci) & 7;
                Frag16* cur = (ci & 1) ? bufB : bufA;
                Frag16* nxt = (ci & 1) ? bufA : bufB;
                if (ci < 7) {
                    const int cn = (c0 + ci + 1) & 7;
                    u64 m = (cn < 4) ? (m1 >> (16 * cn)) : (m2 >> (16 * (cn - 4)));
                    if ((m & 0xFFFFull) != 0xFFFFull) poll_chunk(flags, cn, wv, t, lane);
                    load_chunk(hp, cn, nxt, ring_on);
                }
#pragma unroll
                for (int it = 0; it < 4; ++it) {
                    short8 a  = cur[it].s8[0];
                    short8 b0 = *(const short8*)(wb0 + 1024 + cc * 128 + it * 32);
                    short8 b1 = *(const short8*)(wb1 + 1024 + cc * 128 + it * 32);
                    a0 = __builtin_amdgcn_mfma_f32_16x16x32_bf16(a, b0, a0, 0, 0, 0);
                    a1 = __builtin_amdgcn_mfma_f32_16x16x32_bf16(a, b1, a1, 0, 0, 0);
                }
            }
        }

        // ---- dump g to wave-private LDS rows (no cross-wave traffic)
        const int rr = wv * 16 + quad * 4;
#pragma unroll
        for (int i2 = 0; i2 < 4; ++i2) {
            g_lds[(rr + i2) * G_STRIDE + c16]      = a0[i2];
            g_lds[(rr + i2) * G_STRIDE + 16 + c16] = a1[i2];
        }
        asm volatile("s_waitcnt lgkmcnt(0)" ::: "memory");  // wave-internal LDS order

        // ---- gates: wave-local; c-state in registers
        float hv[2], cv[2];
#pragma unroll
        for (int jj = 0; jj < 2; ++jj) {
            int hl = hl0 + jj;
            float gf = g_lds[grow * G_STRIDE + hl]      + bias[jj];
            float gi = g_lds[grow * G_STRIDE + 8 + hl]  + bias[2 + jj];
            float gg = g_lds[grow * G_STRIDE + 16 + hl] + bias[4 + jj];
            float go = g_lds[grow * G_STRIDE + 24 + hl] + bias[6 + jj];
            float fg = sigm(gf), ig = sigm(gi), og = sigm(go);
            float gt = tanh_(gg);
            float cnew = fg * creg[jj] + ig * gt;
            creg[jj] = cnew;
            cv[jj] = cnew;
            hv[jj] = tanh_(cnew) * og;
        }

        if (t < T_STEPS - 1) {
            // h store: write-through u32 (2 bf16) straight to coherence point.
            // ring mode: buffer t is written exactly once per launch.
            u32 pk = (u32)(u16)bfb(hv[0]) | ((u32)(u16)bfb(hv[1]) << 16);
            u16* hn = hring + (size_t)(ring_on ? t : ((t + 1) & 1)) * HBUF_E;
            __hip_atomic_store((u32*)(hn + (size_t)grow * HD + blk * 8 + hl0), pk,
                               __ATOMIC_RELAXED, __HIP_MEMORY_SCOPE_AGENT);
            // wave-local release: drain own vm ops, then publish per-wave flag.
            asm volatile("s_waitcnt vmcnt(0)" ::: "memory");
            if (lane == 0)
                __hip_atomic_store(&flags[4 * blk + wv], t + 1, __ATOMIC_RELAXED,
                                   __HIP_MEMORY_SCOPE_AGENT);

            // ---- x-side partials for t+1 (fills the flag-propagation window)
            ax0 = (f32x4){0.f,0.f,0.f,0.f};
            ax1 = (f32x4){0.f,0.f,0.f,0.f};
            if (use16) {
                const u16* xp = x16l + (size_t)(t + 1) * HD;
#pragma unroll 8
                for (int kc = 0; kc < 32; ++kc) {
                    short8 a  = *(const short8*)(xp + kc * 32);
                    short8 b0 = *(const short8*)(wb0 + kc * 32);
                    short8 b1 = *(const short8*)(wb1 + kc * 32);
                    ax0 = __builtin_amdgcn_mfma_f32_16x16x32_bf16(a, b0, ax0, 0, 0, 0);
                    ax1 = __builtin_amdgcn_mfma_f32_16x16x32_bf16(a, b1, ax1, 0, 0, 0);
                }
            } else {
                const float* xp = xf_l + (size_t)(t + 1) * HD;
#pragma unroll 4
                for (int kc = 0; kc < 32; ++kc) {
                    float4 fa = *(const float4*)(xp + kc * 32);
                    float4 fb = *(const float4*)(xp + kc * 32 + 4);
                    short8 a = {bfb(fa.x), bfb(fa.y), bfb(fa.z), bfb(fa.w),
                                bfb(fb.x), bfb(fb.y), bfb(fb.z), bfb(fb.w)};
                    short8 b0 = *(const short8*)(wb0 + kc * 32);
                    short8 b1 = *(const short8*)(wb1 + kc * 32);
                    ax0 = __builtin_amdgcn_mfma_f32_16x16x32_bf16(a, b0, ax0, 0, 0, 0);
                    ax1 = __builtin_amdgcn_mfma_f32_16x16x32_bf16(a, b1, ax1, 0, 0, 0);
                }
            }
        } else {
            // final step: write h_T and c_T (wave-private rows)
#pragma unroll
            for (int jj = 0; jj < 2; ++jj) {
                size_t idx = (size_t)grow * HD + blk * 8 + hl0 + jj;
                if (bf16mode) {
                    u16* o = (u16*)outv;
                    __hip_bfloat16 hb = __float2bfloat16(hv[jj]);
                    __hip_bfloat16 cb = __float2bfloat16(cv[jj]);
                    o[idx] = *(u16*)&hb;
                    o[(size_t)BATCH * HD + idx] = *(u16*)&cb;
                } else {
                    float* o = (float*)outv;
                    o[idx] = hv[jj];
                    o[(size_t)BATCH * HD + idx] = cv[jj];
                }
            }
        }
    }
}

extern "C" void kernel_launch(void* const* d_in, const int* in_sizes, int n_in,
                              void* d_out, int out_size, void* d_ws, size_t ws_size,
                              hipStream_t stream) {
    (void)in_sizes; (void)n_in; (void)out_size;
    const void* x   = d_in[0];
    const void* Wii = d_in[1];  const void* Whi = d_in[2];
    const void* Wif = d_in[3];  const void* Whf = d_in[4];
    const void* Wig = d_in[5];  const void* Whg = d_in[6];
    const void* Wio = d_in[7];  const void* Who = d_in[8];
    const void* bii = d_in[9];  const void* bhi = d_in[10];
    const void* bif = d_in[11]; const void* bhf = d_in[12];
    const void* big = d_in[13]; const void* bhg = d_in[14];
    const void* bio = d_in[15]; const void* bho = d_in[16];

    int* flags = (int*)d_ws;                        // 512 per-wave flags (2 KB)
    u16* hring = (u16*)((char*)d_ws + 4096);

    const size_t ring_bytes = (size_t)T_STEPS * HBUF_E * 2;          // 64 MiB
    const size_t xb_bytes   = (size_t)BATCH * T_STEPS * HD * 2;      // 64 MiB
    int ring_on = 0;
    u16* xb = nullptr;
    if (ws_size >= 4096 + ring_bytes + xb_bytes) {
        ring_on = 1;
        xb = (u16*)((char*)d_ws + 4096 + ring_bytes);
    } else if (ws_size >= 4096 + ring_bytes) {
        ring_on = 1;                                 // ring, fp32-x direct
    } else if (ws_size >= 4096 + (size_t)2 * HBUF_E * 2 + xb_bytes) {
        xb = (u16*)((char*)d_ws + 4096 + (size_t)2 * HBUF_E * 2);    // legacy R5
    }

    hipMemsetAsync(d_ws, 0, 4096, stream);
    if (xb)
        hipLaunchKernelGGL(cvt_x_kernel, dim3(2048), dim3(256), 0, stream,
                           x, xb, (BATCH * T_STEPS * HD) / 4);

    hipFuncSetAttribute((const void*)lstm_persistent,
                        hipFuncAttributeMaxDynamicSharedMemorySize, SMEM_BYTES);
    hipLaunchKernelGGL(lstm_persistent, dim3(NBLK), dim3(NTHR), SMEM_BYTES, stream,
                       x, Wif, Wii, Wig, Wio, Whf, Whi, Whg, Who,
                       bif, bii, big, bio, bhf, bhi, bhg, bho,
                       hring, ring_on, xb, flags, d_out);
}